// Round 13
// baseline (25592.618 us; speedup 1.0000x reference)
//
#include <hip/hip_runtime.h>

// PhasedLSTM: S=1024, B=64, H=512, L=2. ONE KERNEL PER PIPELINE PHASE (R11
// structure, XP fused into G0). Kernel q (q=1..1025): G0 blocks compute
// h0[q-1] = LSTM(x[q-1], h0[q-2]) via K=1024 concat GEMM; G1 blocks compute
// h1[q-2] via K=1024 concat GEMM. All inputs of kernel q were produced by
// kernel q-1, so same-stream launch ordering IS the sync (incl. cross-XCD).
// Both roles are instances of the SAME proven machinery (R11's G1 path):
// 32 blocks x 16 units, 128KB LDS weight slice, A staged in swizzled LDS
// chunks, 16x16x32 bf16 MFMA. t<=8 phases: exact fp32 VALU path (time-gate
// k=2phi/RHO reaches -40; gate error amplified ~k^3 -> bf16 insufficient).

#define TPREC 8

// d_ws byte offsets
#define OFF_H0    4096            // 2 slots x [64][512] bf16
#define OFF_H1    266240
#define OFF_H0F   528384          // 2 slots x [512 u][64 b] f32 (early-phase operand)
#define OFF_H1F   1052672
#define OFF_C0    1576960         // [64 b][512 u] f32 cell state
#define OFF_C1    1708032
#define OFF_KTAB  2887680         // [1024 t][2 l][512 u] f32
#define OFF_W0C   7081984         // 32 blk x [64][1024] bf16 ([Wxh0 ; Whh0] K-concat)
#define OFF_W1    11276288        // 32 blk x [64][1024] bf16 ([Wxh1 ; Whh1] K-concat)
                                  // ends 15470592

#define HB_SLOT   65536
#define HF_SLOT   131072

typedef float  f32x4  __attribute__((ext_vector_type(4)));
typedef int    i32x4  __attribute__((ext_vector_type(4)));
typedef __bf16 bf16x8 __attribute__((ext_vector_type(8)));

static __device__ __forceinline__ unsigned short f2bf(float f) {
  unsigned u = __builtin_bit_cast(unsigned, f);
  u += 0x7FFFu + ((u >> 16) & 1u);        // RNE
  return (unsigned short)(u >> 16);
}
static __device__ __forceinline__ int pack2(float a, float b) {
  return (int)((unsigned)f2bf(a) | ((unsigned)f2bf(b) << 16));
}
static __device__ __forceinline__ float sigm(float x) { return 1.0f / (1.0f + __expf(-x)); }
static __device__ __forceinline__ float tanhfast(float x) { return 1.0f - 2.0f / (__expf(2.0f * x) + 1.0f); }

// Cross-kernel ring ops are PLAIN cached accesses: the kernel boundary provides
// ordering + coherence (same-stream dependent launches).
static __device__ __forceinline__ i32x4 ring_load16(const void* p) {
  return *(const i32x4*)p;
}
static __device__ __forceinline__ void ring_storef(void* p, float v) {
  *(float*)p = v;
}
static __device__ __forceinline__ void ring_store_u16(void* p, unsigned v) {
  *(unsigned short*)p = (unsigned short)v;
}

static __device__ __forceinline__ f32x4 mfma16(bf16x8 a, bf16x8 b, f32x4 c) {
  return __builtin_amdgcn_mfma_f32_16x16x32_bf16(a, b, c, 0, 0, 0);
}
static __device__ __forceinline__ bf16x8 lds_frag(const char* p) {
  return __builtin_bit_cast(bf16x8, *(const i32x4*)p);
}

// ---------------- prep: bf16 weight relayout + time-gate table ----------------
__global__ void plstm_prep(const float* __restrict__ Wxh_w, const float* __restrict__ Whh_w,
                           const float* __restrict__ times, const float* __restrict__ tau,
                           const float* __restrict__ s_p, unsigned char* __restrict__ ws) {
  const int idx = blockIdx.x * 256 + threadIdx.x;
  const int stride = gridDim.x * 256;
  // W0C: layer0 [Wxh0 ; Whh0] K-concat, blk g owns u in [g*16,g*16+16)
  for (int e = idx; e < 2097152; e += stride) {
    int g = e >> 16, j = (e >> 10) & 63, k = e & 1023;
    int gate = j >> 4, row = gate * 512 + g * 16 + (j & 15);
    float v = (k < 512) ? Wxh_w[row * 512 + k] : Whh_w[row * 512 + (k - 512)];
    ((unsigned short*)(ws + OFF_W0C))[e] = f2bf(v);
  }
  // W1: layer1 [Wxh1 ; Whh1] K-concat, blk g owns u in [g*16,g*16+16)
  for (int e = idx; e < 2097152; e += stride) {
    int g = e >> 16, j = (e >> 10) & 63, k = e & 1023;
    int gate = j >> 4, row = gate * 512 + g * 16 + (j & 15);
    float v = (k < 512) ? Wxh_w[1048576 + row * 512 + k] : Whh_w[1048576 + row * 512 + (k - 512)];
    ((unsigned short*)(ws + OFF_W1))[e] = f2bf(v);
  }
  // k table: [t][l][u]
  for (int e = idx; e < 1048576; e += stride) {
    int t = e >> 10, r = e & 1023, l = r >> 9, u = r & 511;
    float phi = fmodf(times[t] - s_p[l * 512 + u], tau[l * 512 + u]) / tau[l * 512 + u];
    float kv;
    if (phi < 0.025f)      kv = phi * 40.0f;
    else if (phi < 0.05f)  kv = 2.0f - phi * 40.0f;
    else                   kv = 0.001f * phi;
    ((float*)(ws + OFF_KTAB))[e] = kv;
  }
}

// ---------------- per-phase kernel ----------------
__global__ void __launch_bounds__(256, 1)
plstm_step(const float* __restrict__ xin, const float* __restrict__ bias,
           const float* __restrict__ Wxh_w, const float* __restrict__ Whh_w,
           float* __restrict__ out, unsigned char* __restrict__ wsu, int q) {
  __shared__ char Wl[131072];   // bf16 weight slice [64][1024] swizzled
  __shared__ char Al[16384];    // A staging [64][128] / exact-path staging

  const char* ws = (const char*)wsu;
  char* wsw = (char*)wsu;
  const int bid = blockIdx.x, tid = threadIdx.x;
  const int lane = tid & 63, wv = tid >> 6;
  const int lq = lane >> 4, lr = lane & 15;
  const int rol = bid >> 5;        // 0 = layer0 (fused x+h), 1 = layer1
  const int grp = bid & 31;        // 16 units: [grp*16, grp*16+16)

  // activity: G0 computes t=q-1 (q<=1024); G1 computes t=q-2 (q>=2)
  if (rol == 0 && q > 1024) return;
  if (rol == 1 && q < 2) return;
  const int t = rol ? q - 2 : q - 1;

  const float* ktabp = (const float*)(ws + OFF_KTAB) + (size_t)rol * 512;
  const float* biasL = bias + rol * 2048;
  float* Alf = (float*)Al;

  char* cp   = wsw + (rol ? OFF_C1 : OFF_C0);
  char* hbw  = wsw + (rol ? OFF_H1 : OFF_H0) + (t & 1) * HB_SLOT;
  char* hfw  = wsw + (rol ? OFF_H1F : OFF_H0F) + (t & 1) * HF_SLOT;
  // A-part1/2 sources (fast path, bf16 rings):
  //  rol0: part1 = x[t] (f32, packed), part2 = h0b[t-1]
  //  rol1: part1 = h0b[t],             part2 = h1b[t-1]
  const char* s1b = ws + OFF_H0 + ((rol ? t : t - 1) & 1) * HB_SLOT;
  const char* s2b = ws + (rol ? OFF_H1 : OFF_H0) + ((t - 1) & 1) * HB_SLOT;
  const float* xs = xin + (size_t)t * 32768;

  if (t > TPREC) {
    // ================ bf16 MFMA fast path (proven G1 machinery) ================
    // Wl fill: [64][1024] slice, swizzle byte ^= (row&7)<<4
    {
      const char* wsrc = ws + (rol ? OFF_W1 : OFF_W0C) + grp * 131072;
      for (int e = tid * 8; e < 65536; e += 2048) {
        i32x4 v = *(const i32x4*)(wsrc + e * 2);
        int row = e >> 10;
        *(i32x4*)(Wl + ((e * 2) ^ ((row & 7) << 4))) = v;
      }
    }
    const int ucol = grp * 16 + lr;
    float bs[4];
#pragma unroll
    for (int gt = 0; gt < 4; ++gt) bs[gt] = biasL[gt * 512 + ucol];
    const float kk = ktabp[(size_t)t * 1024 + ucol];
    float cold[4];
#pragma unroll
    for (int i = 0; i < 4; ++i) {
      const int b = wv * 16 + lq * 4 + i;
      cold[i] = *(const float*)(cp + (b * 512 + ucol) * 4);
    }
    // prefetch A-part2 + (rol1) A-part1 into regs (bf16 rings)
    i32x4 areg[32];
#pragma unroll
    for (int kc = 0; kc < 4; ++kc)
#pragma unroll
      for (int it = 0; it < 4; ++it) {
        const int idx = it * 2048 + tid * 8, row = idx >> 7, col = idx & 127;
        if (rol)
          areg[kc * 4 + it] = ring_load16(s1b + (row * 512 + kc * 128 + col) * 2);
        areg[16 + kc * 4 + it] = ring_load16(s2b + (row * 512 + kc * 128 + col) * 2);
      }
    f32x4 acc[4] = {};
#pragma unroll
    for (int kc = 0; kc < 8; ++kc) {
      __syncthreads();
#pragma unroll
      for (int it = 0; it < 4; ++it) {
        const int idx = it * 2048 + tid * 8, row = idx >> 7, col = idx & 127;
        i32x4 v;
        if (!rol && kc < 4) {
          // pack x[t] f32 -> bf16 on the fly
          const float* p = xs + row * 512 + kc * 128 + col;
          const f32x4 lo = *(const f32x4*)p, hi = *(const f32x4*)(p + 4);
          v[0] = pack2(lo[0], lo[1]); v[1] = pack2(lo[2], lo[3]);
          v[2] = pack2(hi[0], hi[1]); v[3] = pack2(hi[2], hi[3]);
        } else {
          v = areg[(rol ? (kc < 4 ? kc : kc + 12) : kc + 12) * 4 + it];
        }
        *(i32x4*)(Al + (((row * 128 + col) * 2) ^ ((row & 7) << 4))) = v;
      }
      __syncthreads();
#pragma unroll
      for (int ks = 0; ks < 4; ++ks) {
        const int b = wv * 16 + lr;
        const bf16x8 af = lds_frag(Al + (((b * 128 + ks * 32 + lq * 8) * 2) ^ ((b & 7) << 4)));
#pragma unroll
        for (int gt = 0; gt < 4; ++gt) {
          const int j = gt * 16 + lr;
          const bf16x8 bf = lds_frag(Wl + (((j * 1024 + kc * 128 + ks * 32 + lq * 8) * 2) ^ ((j & 7) << 4)));
          acc[gt] = mfma16(af, bf, acc[gt]);
        }
      }
    }
#pragma unroll
    for (int i = 0; i < 4; ++i) {
      const int b = wv * 16 + lq * 4 + i;
      const float gi = acc[0][i] + bs[0];
      const float gf = acc[1][i] + bs[1];
      const float gz = acc[2][i] + bs[2];
      const float go = acc[3][i] + bs[3];
      const float itg = sigm(gi) * kk;
      const float ftg = sigm(gf + 1.0f - kk);
      const float gtg = tanhfast(gz) * kk;
      const float otg = sigm(go) * kk;
      const float cn = ftg * cold[i] + itg * gtg;
      const float hn = otg * tanhfast(cn);
      *(float*)(cp + (b * 512 + ucol) * 4) = cn;
      ring_store_u16(hbw + (b * 512 + ucol) * 2, (unsigned)f2bf(hn));
      if (rol) out[(size_t)t * 32768 + b * 512 + ucol] = hn;
      if (t == 1023) {
        out[33554432 + rol * 32768 + b * 512 + ucol] = hn;
        out[33554432 + 65536 + rol * 32768 + b * 512 + ucol] = cn;
      }
    }
  } else {
    // ================ exact fp32 path (proven G1-exact machinery) ================
    const int rp = tid >> 4, bq = tid & 15;
    const int gate = rp >> 2;
    const int uoff0 = (rp & 3) * 4;
    const size_t wbase = (size_t)(gate * 512 + grp * 16 + uoff0) * 512 + (rol ? 1048576 : 0);
    const float* wx4 = Wxh_w + wbase;   // pairs with A-part1 (x or h0[t])
    const float* wh4 = Whh_w + wbase;   // pairs with A-part2 (h0[t-1] or h1[t-1])
    const char* s1f = ws + OFF_H0F + ((rol ? t : t - 1) & 1) * HF_SLOT;
    const char* s2f = ws + (rol ? OFF_H1F : OFF_H0F) + ((t - 1) & 1) * HF_SLOT;
    f32x4 acc4[4] = {};
    for (int kc = 0; kc < 16; ++kc) {
      const int k0 = (kc & 7) * 64;
      const float* wsel = (kc < 8) ? (wx4 + k0) : (wh4 + k0);
      __syncthreads();
      if (!rol && kc < 8) {
        // stage x[t] chunk with transpose: [b][k] -> Alf[k][b]
        for (int i = 0; i < 4; ++i) {
          int qi = tid + 256 * i, b = qi >> 4, k4 = qi & 15;
          f32x4 v = *(const f32x4*)(xs + b * 512 + k0 + k4 * 4);
#pragma unroll
          for (int j = 0; j < 4; ++j) Alf[(k4 * 4 + j) * 64 + b] = v[j];
        }
      } else {
        const char* hsrc = (kc < 8) ? s1f : s2f;
        for (int i = 0; i < 4; ++i) {
          int qi = tid + 256 * i, k = qi >> 4, b4 = qi & 15;
          i32x4 v = ring_load16(hsrc + ((k0 + k) * 64 + b4 * 4) * 4);
          *(i32x4*)(Alf + k * 64 + b4 * 4) = v;
        }
      }
      __syncthreads();
      for (int kb = 0; kb < 16; ++kb) {
        f32x4 w4[4];
#pragma unroll
        for (int r = 0; r < 4; ++r) w4[r] = *(const f32x4*)(wsel + r * 512 + kb * 4);
#pragma unroll
        for (int ks = 0; ks < 4; ++ks) {
          f32x4 hv = *(const f32x4*)(Alf + (kb * 4 + ks) * 64 + bq * 4);
#pragma unroll
          for (int r = 0; r < 4; ++r) acc4[r] += w4[r][ks] * hv;
        }
      }
    }
    __syncthreads();
#pragma unroll
    for (int r = 0; r < 4; ++r)
      *(f32x4*)(Alf + (rp * 4 + r) * 64 + bq * 4) = acc4[r];
    __syncthreads();
    for (int i = 0; i < 4; ++i) {
      int e = tid + 256 * i;
      int u = e >> 6, b = e & 63;
      int ucol = grp * 16 + u;
      float g4[4];
#pragma unroll
      for (int gt = 0; gt < 4; ++gt)
        g4[gt] = Alf[(gt * 16 + u) * 64 + b] + biasL[gt * 512 + ucol];
      const float kk = ktabp[(size_t)t * 1024 + ucol];
      const float cold = *(const float*)(cp + (b * 512 + ucol) * 4);
      const float itg = sigm(g4[0]) * kk;
      const float ftg = sigm(g4[1] + 1.0f - kk);
      const float gtg = tanhfast(g4[2]) * kk;
      const float otg = sigm(g4[3]) * kk;
      const float cn = ftg * cold + itg * gtg;
      const float hn = otg * tanhfast(cn);
      *(float*)(cp + (b * 512 + ucol) * 4) = cn;
      ring_store_u16(hbw + (b * 512 + ucol) * 2, (unsigned)f2bf(hn));
      ring_storef(hfw + (ucol * 64 + b) * 4, hn);
      if (rol) out[(size_t)t * 32768 + b * 512 + ucol] = hn;
    }
  }
}

extern "C" void kernel_launch(void* const* d_in, const int* in_sizes, int n_in,
                              void* d_out, int out_size, void* d_ws, size_t ws_size,
                              hipStream_t stream) {
  (void)in_sizes; (void)n_in; (void)out_size; (void)ws_size;
  const float* inputs = (const float*)d_in[0];
  const float* times  = (const float*)d_in[1];
  const float* Wxh_w  = (const float*)d_in[2];
  const float* Wxh_b  = (const float*)d_in[3];
  const float* Whh_w  = (const float*)d_in[4];
  const float* tau    = (const float*)d_in[5];
  const float* s_p    = (const float*)d_in[6];
  unsigned char* ws = (unsigned char*)d_ws;
  float* out = (float*)d_out;

  hipMemsetAsync(ws + OFF_H0 + HB_SLOT, 0, HB_SLOT, stream);    // h0 bf16 slot1 = 0
  hipMemsetAsync(ws + OFF_H1 + HB_SLOT, 0, HB_SLOT, stream);    // h1 bf16 slot1 = 0
  hipMemsetAsync(ws + OFF_H0F + HF_SLOT, 0, HF_SLOT, stream);   // h0 f32 slot1 = 0
  hipMemsetAsync(ws + OFF_H1F + HF_SLOT, 0, HF_SLOT, stream);   // h1 f32 slot1 = 0
  hipMemsetAsync(ws + OFF_C0, 0, 131072, stream);               // c0 = 0
  hipMemsetAsync(ws + OFF_C1, 0, 131072, stream);               // c1 = 0

  plstm_prep<<<8192, 256, 0, stream>>>(Wxh_w, Whh_w, times, tau, s_p, ws);

  for (int q = 1; q <= 1025; ++q)
    plstm_step<<<64, 256, 0, stream>>>(inputs, Wxh_b, Wxh_w, Whh_w, out, ws, q);
}

// Round 14
// 16968.843 us; speedup vs baseline: 1.5082x; 1.5082x over previous
//
#include <hip/hip_runtime.h>

// PhasedLSTM: S=1024, B=64, H=512, L=2. ONE KERNEL PER PIPELINE PHASE (R11
// structure, XP fused into G0). Kernel q (q=1..1025): G0 blocks compute
// h0[q-1] = LSTM(x[q-1], h0[q-2]) via K=1024 concat GEMM; G1 blocks compute
// h1[q-2] via K=1024 concat GEMM. All inputs of kernel q were produced by
// kernel q-1, so same-stream launch ordering IS the sync (incl. cross-XCD).
// R14 fix vs R13: staging index areg[kc*4+it] (R13 had OOB areg[(kc+12)*4+it]
// -> UB + scratch demotion = 2x slowdown, rule #20); x->bf16 pack moved into
// the register prefetch so no HBM latency sits between staging barriers.
// t<=8 phases: exact fp32 VALU path (time-gate k=2phi/RHO reaches -40; gate
// error amplified ~k^3 -> bf16 insufficient). t>=9: k<=1 -> bf16 MFMA path.

#define TPREC 8

// d_ws byte offsets
#define OFF_H0    4096            // 2 slots x [64][512] bf16
#define OFF_H1    266240
#define OFF_H0F   528384          // 2 slots x [512 u][64 b] f32 (early-phase operand)
#define OFF_H1F   1052672
#define OFF_C0    1576960         // [64 b][512 u] f32 cell state
#define OFF_C1    1708032
#define OFF_KTAB  2887680         // [1024 t][2 l][512 u] f32
#define OFF_W0C   7081984         // 32 blk x [64][1024] bf16 ([Wxh0 ; Whh0] K-concat)
#define OFF_W1    11276288        // 32 blk x [64][1024] bf16 ([Wxh1 ; Whh1] K-concat)
                                  // ends 15470592

#define HB_SLOT   65536
#define HF_SLOT   131072

typedef float  f32x4  __attribute__((ext_vector_type(4)));
typedef int    i32x4  __attribute__((ext_vector_type(4)));
typedef __bf16 bf16x8 __attribute__((ext_vector_type(8)));

static __device__ __forceinline__ unsigned short f2bf(float f) {
  unsigned u = __builtin_bit_cast(unsigned, f);
  u += 0x7FFFu + ((u >> 16) & 1u);        // RNE
  return (unsigned short)(u >> 16);
}
static __device__ __forceinline__ int pack2(float a, float b) {
  return (int)((unsigned)f2bf(a) | ((unsigned)f2bf(b) << 16));
}
static __device__ __forceinline__ float sigm(float x) { return 1.0f / (1.0f + __expf(-x)); }
static __device__ __forceinline__ float tanhfast(float x) { return 1.0f - 2.0f / (__expf(2.0f * x) + 1.0f); }

// Cross-kernel ring ops are PLAIN cached accesses: the kernel boundary provides
// ordering + coherence (same-stream dependent launches).
static __device__ __forceinline__ i32x4 ring_load16(const void* p) {
  return *(const i32x4*)p;
}
static __device__ __forceinline__ void ring_storef(void* p, float v) {
  *(float*)p = v;
}
static __device__ __forceinline__ void ring_store_u16(void* p, unsigned v) {
  *(unsigned short*)p = (unsigned short)v;
}

static __device__ __forceinline__ f32x4 mfma16(bf16x8 a, bf16x8 b, f32x4 c) {
  return __builtin_amdgcn_mfma_f32_16x16x32_bf16(a, b, c, 0, 0, 0);
}
static __device__ __forceinline__ bf16x8 lds_frag(const char* p) {
  return __builtin_bit_cast(bf16x8, *(const i32x4*)p);
}

// ---------------- prep: bf16 weight relayout + time-gate table ----------------
__global__ void plstm_prep(const float* __restrict__ Wxh_w, const float* __restrict__ Whh_w,
                           const float* __restrict__ times, const float* __restrict__ tau,
                           const float* __restrict__ s_p, unsigned char* __restrict__ ws) {
  const int idx = blockIdx.x * 256 + threadIdx.x;
  const int stride = gridDim.x * 256;
  // W0C: layer0 [Wxh0 ; Whh0] K-concat, blk g owns u in [g*16,g*16+16)
  for (int e = idx; e < 2097152; e += stride) {
    int g = e >> 16, j = (e >> 10) & 63, k = e & 1023;
    int gate = j >> 4, row = gate * 512 + g * 16 + (j & 15);
    float v = (k < 512) ? Wxh_w[row * 512 + k] : Whh_w[row * 512 + (k - 512)];
    ((unsigned short*)(ws + OFF_W0C))[e] = f2bf(v);
  }
  // W1: layer1 [Wxh1 ; Whh1] K-concat, blk g owns u in [g*16,g*16+16)
  for (int e = idx; e < 2097152; e += stride) {
    int g = e >> 16, j = (e >> 10) & 63, k = e & 1023;
    int gate = j >> 4, row = gate * 512 + g * 16 + (j & 15);
    float v = (k < 512) ? Wxh_w[1048576 + row * 512 + k] : Whh_w[1048576 + row * 512 + (k - 512)];
    ((unsigned short*)(ws + OFF_W1))[e] = f2bf(v);
  }
  // k table: [t][l][u]
  for (int e = idx; e < 1048576; e += stride) {
    int t = e >> 10, r = e & 1023, l = r >> 9, u = r & 511;
    float phi = fmodf(times[t] - s_p[l * 512 + u], tau[l * 512 + u]) / tau[l * 512 + u];
    float kv;
    if (phi < 0.025f)      kv = phi * 40.0f;
    else if (phi < 0.05f)  kv = 2.0f - phi * 40.0f;
    else                   kv = 0.001f * phi;
    ((float*)(ws + OFF_KTAB))[e] = kv;
  }
}

// ---------------- per-phase kernel ----------------
__global__ void __launch_bounds__(256, 1)
plstm_step(const float* __restrict__ xin, const float* __restrict__ bias,
           const float* __restrict__ Wxh_w, const float* __restrict__ Whh_w,
           float* __restrict__ out, unsigned char* __restrict__ wsu, int q) {
  __shared__ char Wl[131072];   // bf16 weight slice [64][1024] swizzled
  __shared__ char Al[16384];    // A staging [64][128] / exact-path staging

  const char* ws = (const char*)wsu;
  char* wsw = (char*)wsu;
  const int bid = blockIdx.x, tid = threadIdx.x;
  const int lane = tid & 63, wv = tid >> 6;
  const int lq = lane >> 4, lr = lane & 15;
  const int rol = bid >> 5;        // 0 = layer0 (fused x+h), 1 = layer1
  const int grp = bid & 31;        // 16 units: [grp*16, grp*16+16)

  // activity: G0 computes t=q-1 (q<=1024); G1 computes t=q-2 (q>=2)
  if (rol == 0 && q > 1024) return;
  if (rol == 1 && q < 2) return;
  const int t = rol ? q - 2 : q - 1;

  const float* ktabp = (const float*)(ws + OFF_KTAB) + (size_t)rol * 512;
  const float* biasL = bias + rol * 2048;
  float* Alf = (float*)Al;

  char* cp   = wsw + (rol ? OFF_C1 : OFF_C0);
  char* hbw  = wsw + (rol ? OFF_H1 : OFF_H0) + (t & 1) * HB_SLOT;
  char* hfw  = wsw + (rol ? OFF_H1F : OFF_H0F) + (t & 1) * HF_SLOT;
  // A-part1/2 sources (fast path, bf16 rings):
  //  rol0: part1 = x[t] (f32, packed in prefetch), part2 = h0b[t-1]
  //  rol1: part1 = h0b[t],                         part2 = h1b[t-1]
  const char* s1b = ws + OFF_H0 + ((rol ? t : t - 1) & 1) * HB_SLOT;
  const char* s2b = ws + (rol ? OFF_H1 : OFF_H0) + ((t - 1) & 1) * HB_SLOT;
  const float* xs = xin + (size_t)t * 32768;

  if (t > TPREC) {
    // ================ bf16 MFMA fast path ================
    // Wl fill: [64][1024] slice, swizzle byte ^= (row&7)<<4
    {
      const char* wsrc = ws + (rol ? OFF_W1 : OFF_W0C) + grp * 131072;
      for (int e = tid * 8; e < 65536; e += 2048) {
        i32x4 v = *(const i32x4*)(wsrc + e * 2);
        int row = e >> 10;
        *(i32x4*)(Wl + ((e * 2) ^ ((row & 7) << 4))) = v;
      }
    }
    const int ucol = grp * 16 + lr;
    float bs[4];
#pragma unroll
    for (int gt = 0; gt < 4; ++gt) bs[gt] = biasL[gt * 512 + ucol];
    const float kk = ktabp[(size_t)t * 1024 + ucol];
    float cold[4];
#pragma unroll
    for (int i = 0; i < 4; ++i) {
      const int b = wv * 16 + lq * 4 + i;
      cold[i] = *(const float*)(cp + (b * 512 + ucol) * 4);
    }
    // prefetch full A into regs: part1 chunks -> areg[0..15], part2 -> areg[16..31]
    i32x4 areg[32];
#pragma unroll
    for (int kc = 0; kc < 4; ++kc)
#pragma unroll
      for (int it = 0; it < 4; ++it) {
        const int idx = it * 2048 + tid * 8, row = idx >> 7, col = idx & 127;
        if (rol) {
          areg[kc * 4 + it] = ring_load16(s1b + (row * 512 + kc * 128 + col) * 2);
        } else {
          const float* p = xs + row * 512 + kc * 128 + col;
          const f32x4 lo = *(const f32x4*)p, hi = *(const f32x4*)(p + 4);
          i32x4 v;
          v[0] = pack2(lo[0], lo[1]); v[1] = pack2(lo[2], lo[3]);
          v[2] = pack2(hi[0], hi[1]); v[3] = pack2(hi[2], hi[3]);
          areg[kc * 4 + it] = v;
        }
        areg[16 + kc * 4 + it] = ring_load16(s2b + (row * 512 + kc * 128 + col) * 2);
      }
    f32x4 acc[4] = {};
#pragma unroll
    for (int kc = 0; kc < 8; ++kc) {
      __syncthreads();
#pragma unroll
      for (int it = 0; it < 4; ++it) {
        const int idx = it * 2048 + tid * 8, row = idx >> 7, col = idx & 127;
        *(i32x4*)(Al + (((row * 128 + col) * 2) ^ ((row & 7) << 4))) = areg[kc * 4 + it];
      }
      __syncthreads();
#pragma unroll
      for (int ks = 0; ks < 4; ++ks) {
        const int b = wv * 16 + lr;
        const bf16x8 af = lds_frag(Al + (((b * 128 + ks * 32 + lq * 8) * 2) ^ ((b & 7) << 4)));
#pragma unroll
        for (int gt = 0; gt < 4; ++gt) {
          const int j = gt * 16 + lr;
          const bf16x8 bf = lds_frag(Wl + (((j * 1024 + kc * 128 + ks * 32 + lq * 8) * 2) ^ ((j & 7) << 4)));
          acc[gt] = mfma16(af, bf, acc[gt]);
        }
      }
    }
#pragma unroll
    for (int i = 0; i < 4; ++i) {
      const int b = wv * 16 + lq * 4 + i;
      const float gi = acc[0][i] + bs[0];
      const float gf = acc[1][i] + bs[1];
      const float gz = acc[2][i] + bs[2];
      const float go = acc[3][i] + bs[3];
      const float itg = sigm(gi) * kk;
      const float ftg = sigm(gf + 1.0f - kk);
      const float gtg = tanhfast(gz) * kk;
      const float otg = sigm(go) * kk;
      const float cn = ftg * cold[i] + itg * gtg;
      const float hn = otg * tanhfast(cn);
      *(float*)(cp + (b * 512 + ucol) * 4) = cn;
      ring_store_u16(hbw + (b * 512 + ucol) * 2, (unsigned)f2bf(hn));
      if (rol) out[(size_t)t * 32768 + b * 512 + ucol] = hn;
      if (t == 1023) {
        out[33554432 + rol * 32768 + b * 512 + ucol] = hn;
        out[33554432 + 65536 + rol * 32768 + b * 512 + ucol] = cn;
      }
    }
  } else {
    // ================ exact fp32 path (proven G1-exact machinery) ================
    const int rp = tid >> 4, bq = tid & 15;
    const int gate = rp >> 2;
    const int uoff0 = (rp & 3) * 4;
    const size_t wbase = (size_t)(gate * 512 + grp * 16 + uoff0) * 512 + (rol ? 1048576 : 0);
    const float* wx4 = Wxh_w + wbase;   // pairs with A-part1 (x or h0[t])
    const float* wh4 = Whh_w + wbase;   // pairs with A-part2 (h0[t-1] or h1[t-1])
    const char* s1f = ws + OFF_H0F + ((rol ? t : t - 1) & 1) * HF_SLOT;
    const char* s2f = ws + (rol ? OFF_H1F : OFF_H0F) + ((t - 1) & 1) * HF_SLOT;
    f32x4 acc4[4] = {};
    for (int kc = 0; kc < 16; ++kc) {
      const int k0 = (kc & 7) * 64;
      const float* wsel = (kc < 8) ? (wx4 + k0) : (wh4 + k0);
      __syncthreads();
      if (!rol && kc < 8) {
        // stage x[t] chunk with transpose: [b][k] -> Alf[k][b]
        for (int i = 0; i < 4; ++i) {
          int qi = tid + 256 * i, b = qi >> 4, k4 = qi & 15;
          f32x4 v = *(const f32x4*)(xs + b * 512 + k0 + k4 * 4);
#pragma unroll
          for (int j = 0; j < 4; ++j) Alf[(k4 * 4 + j) * 64 + b] = v[j];
        }
      } else {
        const char* hsrc = (kc < 8) ? s1f : s2f;
        for (int i = 0; i < 4; ++i) {
          int qi = tid + 256 * i, k = qi >> 4, b4 = qi & 15;
          i32x4 v = ring_load16(hsrc + ((k0 + k) * 64 + b4 * 4) * 4);
          *(i32x4*)(Alf + k * 64 + b4 * 4) = v;
        }
      }
      __syncthreads();
      for (int kb = 0; kb < 16; ++kb) {
        f32x4 w4[4];
#pragma unroll
        for (int r = 0; r < 4; ++r) w4[r] = *(const f32x4*)(wsel + r * 512 + kb * 4);
#pragma unroll
        for (int ks = 0; ks < 4; ++ks) {
          f32x4 hv = *(const f32x4*)(Alf + (kb * 4 + ks) * 64 + bq * 4);
#pragma unroll
          for (int r = 0; r < 4; ++r) acc4[r] += w4[r][ks] * hv;
        }
      }
    }
    __syncthreads();
#pragma unroll
    for (int r = 0; r < 4; ++r)
      *(f32x4*)(Alf + (rp * 4 + r) * 64 + bq * 4) = acc4[r];
    __syncthreads();
    for (int i = 0; i < 4; ++i) {
      int e = tid + 256 * i;
      int u = e >> 6, b = e & 63;
      int ucol = grp * 16 + u;
      float g4[4];
#pragma unroll
      for (int gt = 0; gt < 4; ++gt)
        g4[gt] = Alf[(gt * 16 + u) * 64 + b] + biasL[gt * 512 + ucol];
      const float kk = ktabp[(size_t)t * 1024 + ucol];
      const float cold = *(const float*)(cp + (b * 512 + ucol) * 4);
      const float itg = sigm(g4[0]) * kk;
      const float ftg = sigm(g4[1] + 1.0f - kk);
      const float gtg = tanhfast(g4[2]) * kk;
      const float otg = sigm(g4[3]) * kk;
      const float cn = ftg * cold + itg * gtg;
      const float hn = otg * tanhfast(cn);
      *(float*)(cp + (b * 512 + ucol) * 4) = cn;
      ring_store_u16(hbw + (b * 512 + ucol) * 2, (unsigned)f2bf(hn));
      ring_storef(hfw + (ucol * 64 + b) * 4, hn);
      if (rol) out[(size_t)t * 32768 + b * 512 + ucol] = hn;
    }
  }
}

extern "C" void kernel_launch(void* const* d_in, const int* in_sizes, int n_in,
                              void* d_out, int out_size, void* d_ws, size_t ws_size,
                              hipStream_t stream) {
  (void)in_sizes; (void)n_in; (void)out_size; (void)ws_size;
  const float* inputs = (const float*)d_in[0];
  const float* times  = (const float*)d_in[1];
  const float* Wxh_w  = (const float*)d_in[2];
  const float* Wxh_b  = (const float*)d_in[3];
  const float* Whh_w  = (const float*)d_in[4];
  const float* tau    = (const float*)d_in[5];
  const float* s_p    = (const float*)d_in[6];
  unsigned char* ws = (unsigned char*)d_ws;
  float* out = (float*)d_out;

  hipMemsetAsync(ws + OFF_H0 + HB_SLOT, 0, HB_SLOT, stream);    // h0 bf16 slot1 = 0
  hipMemsetAsync(ws + OFF_H1 + HB_SLOT, 0, HB_SLOT, stream);    // h1 bf16 slot1 = 0
  hipMemsetAsync(ws + OFF_H0F + HF_SLOT, 0, HF_SLOT, stream);   // h0 f32 slot1 = 0
  hipMemsetAsync(ws + OFF_H1F + HF_SLOT, 0, HF_SLOT, stream);   // h1 f32 slot1 = 0
  hipMemsetAsync(ws + OFF_C0, 0, 131072, stream);               // c0 = 0
  hipMemsetAsync(ws + OFF_C1, 0, 131072, stream);               // c1 = 0

  plstm_prep<<<8192, 256, 0, stream>>>(Wxh_w, Whh_w, times, tau, s_p, ws);

  for (int q = 1; q <= 1025; ++q)
    plstm_step<<<64, 256, 0, stream>>>(inputs, Wxh_b, Wxh_w, Whh_w, out, ws, q);
}

// Round 15
// 13682.341 us; speedup vs baseline: 1.8705x; 1.2402x over previous
//
#include <hip/hip_runtime.h>

// PhasedLSTM: S=1024, B=64, H=512, L=2. ONE KERNEL PER PIPELINE PHASE, 4 uniform
// roles x 32 blocks (grid 128), each role = SAME K=512/N=64 machinery, 64KB LDS
// weight slice. Kernel q: XP->Xpre[q] ; G0->h0[q-1] ; XQ->P1[q-2]=h0@Wxh1^T+b1 ;
// G1->h1[q-3]=LSTM(P1, h1@Whh1^T). All inputs of kernel q produced by kernel q-1
// -> same-stream launch ordering IS the sync (incl. cross-XCD). R14 lesson: keep
// producer GEMMs in PARALLEL roles (serialized same-stream kernels cost
// max-over-blocks); R11 lesson: LDS-stage both MFMA operands; R13 lesson: only
// static register indexing. t<=8: exact fp32 VALU paths (time-gate k=2phi/RHO
// reaches -40; gate error amplified ~k^3). t>=9: k<=1 -> bf16 MFMA.

#define TPREC 8

// d_ws byte offsets
#define OFF_H0B   4096            // 2 slots x [64 b][512 u] bf16
#define OFF_H1B   135168
#define OFF_H0F   266240          // 2 slots x [512 u][64 b] f32
#define OFF_H1F   528384
#define OFF_C0    790528          // [64 b][512 u] f32
#define OFF_C1    921600
#define OFF_XPRE  1052672         // 2 slots x [64 b][2048 n] f32 (incl bias0)
#define OFF_P1    2101248         // 2 slots x [64 b][2048 n] f32 (incl bias1)
#define OFF_KTAB  3149824         // [1024 t][2 l][512 u] f32
#define OFF_WXP   7344128         // 32 blk x [64][512] bf16  Wxh0, plain rows
#define OFF_WH0   9441280         // 32 blk x [64][512] bf16  Whh0, gate-grouped
#define OFF_WX1   11538432        // 32 blk x [64][512] bf16  Wxh1, gate-grouped
#define OFF_WH1   13635584        // 32 blk x [64][512] bf16  Whh1, gate-grouped
                                  // ends 15732736 (ws >= 22.5 MB proven in R3/R4)
#define HB_SLOT   65536
#define HF_SLOT   131072
#define PX_SLOT   524288

typedef float  f32x4  __attribute__((ext_vector_type(4)));
typedef int    i32x4  __attribute__((ext_vector_type(4)));
typedef __bf16 bf16x8 __attribute__((ext_vector_type(8)));

static __device__ __forceinline__ unsigned short f2bf(float f) {
  unsigned u = __builtin_bit_cast(unsigned, f);
  u += 0x7FFFu + ((u >> 16) & 1u);        // RNE
  return (unsigned short)(u >> 16);
}
static __device__ __forceinline__ int pack2(float a, float b) {
  return (int)((unsigned)f2bf(a) | ((unsigned)f2bf(b) << 16));
}
static __device__ __forceinline__ float sigm(float x) { return 1.0f / (1.0f + __expf(-x)); }
static __device__ __forceinline__ float tanhfast(float x) { return 1.0f - 2.0f / (__expf(2.0f * x) + 1.0f); }

// Cross-kernel buffers are PLAIN cached accesses: the kernel boundary provides
// ordering + coherence (same-stream dependent launches).
static __device__ __forceinline__ i32x4 ring_load16(const void* p) {
  return *(const i32x4*)p;
}
static __device__ __forceinline__ float ring_loadf(const void* p) {
  return *(const float*)p;
}
static __device__ __forceinline__ void ring_storef(void* p, float v) {
  *(float*)p = v;
}
static __device__ __forceinline__ void ring_store_u16(void* p, unsigned v) {
  *(unsigned short*)p = (unsigned short)v;
}

static __device__ __forceinline__ f32x4 mfma16(bf16x8 a, bf16x8 b, f32x4 c) {
  return __builtin_amdgcn_mfma_f32_16x16x32_bf16(a, b, c, 0, 0, 0);
}
static __device__ __forceinline__ bf16x8 lds_frag(const char* p) {
  return __builtin_bit_cast(bf16x8, *(const i32x4*)p);
}

// ---------------- prep: bf16 weight relayout + time-gate table ----------------
__global__ void plstm_prep(const float* __restrict__ Wxh_w, const float* __restrict__ Whh_w,
                           const float* __restrict__ times, const float* __restrict__ tau,
                           const float* __restrict__ s_p, unsigned char* __restrict__ ws) {
  const int idx = blockIdx.x * 256 + threadIdx.x;
  const int stride = gridDim.x * 256;
  unsigned short* wxp = (unsigned short*)(ws + OFF_WXP);
  unsigned short* wh0 = (unsigned short*)(ws + OFF_WH0);
  unsigned short* wx1 = (unsigned short*)(ws + OFF_WX1);
  unsigned short* wh1 = (unsigned short*)(ws + OFF_WH1);
  // each array: 32 blk x [64 j][512 k]
  for (int e = idx; e < 1048576; e += stride) {
    int blk = e >> 15, j = (e >> 9) & 63, k = e & 511;
    // XP: plain rows n = blk*64 + j of Wxh0
    wxp[e] = f2bf(Wxh_w[(size_t)(blk * 64 + j) * 512 + k]);
    // gate-grouped: j = gate*16 + uoff, unit = blk*16 + uoff
    int gate = j >> 4, row = gate * 512 + blk * 16 + (j & 15);
    wh0[e] = f2bf(Whh_w[(size_t)row * 512 + k]);
    wx1[e] = f2bf(Wxh_w[1048576 + (size_t)row * 512 + k]);
    wh1[e] = f2bf(Whh_w[1048576 + (size_t)row * 512 + k]);
  }
  // k table: [t][l][u]
  for (int e = idx; e < 1048576; e += stride) {
    int t = e >> 10, r = e & 1023, l = r >> 9, u = r & 511;
    float phi = fmodf(times[t] - s_p[l * 512 + u], tau[l * 512 + u]) / tau[l * 512 + u];
    float kv;
    if (phi < 0.025f)      kv = phi * 40.0f;
    else if (phi < 0.05f)  kv = 2.0f - phi * 40.0f;
    else                   kv = 0.001f * phi;
    ((float*)(ws + OFF_KTAB))[e] = kv;
  }
}

// ---------------- per-phase kernel: 4 roles x 32 blocks ----------------
__global__ void __launch_bounds__(256, 1)
plstm_step(const float* __restrict__ xin, const float* __restrict__ bias,
           const float* __restrict__ Wxh_w, const float* __restrict__ Whh_w,
           float* __restrict__ out, unsigned char* __restrict__ wsu, int q) {
  __shared__ char Wl[65536];    // [64][512] bf16 weight slice, swizzled
  __shared__ char Al[16384];    // fast: [64][128] bf16 chunk ; exact: [64 k][64 b] f32

  const char* ws = (const char*)wsu;
  char* wsw = (char*)wsu;
  const int bid = blockIdx.x, tid = threadIdx.x;
  const int lane = tid & 63, wv = tid >> 6;
  const int lq = lane >> 4, lr = lane & 15;
  const int role = bid >> 5, grp = bid & 31;

  // activity windows (pipeline: XP t=q, G0 t=q-1, XQ t=q-2, G1 t=q-3)
  int t;
  if (role == 0)      { if (q > 1023) return; t = q; }
  else if (role == 1) { if (q < 1 || q > 1024) return; t = q - 1; }
  else if (role == 2) { if (q < 2 || q > 1025) return; t = q - 2; }
  else                { if (q < 3) return; t = q - 3; }

  const float* ktabp = (const float*)(ws + OFF_KTAB);
  float* Alf = (float*)Al;
  const float* xs = xin + (size_t)t * 32768;

  // role-specific pointers
  const char* aring = nullptr;        // bf16 A source (roles 1,2,3)
  const char* Pp = nullptr;           // f32 pre-activation source (roles 1,3)
  char* dst = nullptr;                // f32 dest (roles 0,2)
  char* cp = nullptr; char* hbw = nullptr; char* hfw = nullptr;
  if (role == 0) {
    dst = wsw + OFF_XPRE + (t & 1) * PX_SLOT;
  } else if (role == 1) {
    aring = ws + OFF_H0B + ((t - 1) & 1) * HB_SLOT;
    Pp = ws + OFF_XPRE + (t & 1) * PX_SLOT;
    cp = wsw + OFF_C0; hbw = wsw + OFF_H0B + (t & 1) * HB_SLOT;
    hfw = wsw + OFF_H0F + (t & 1) * HF_SLOT;
  } else if (role == 2) {
    aring = ws + OFF_H0B + (t & 1) * HB_SLOT;
    dst = wsw + OFF_P1 + (t & 1) * PX_SLOT;
  } else {
    aring = ws + OFF_H1B + ((t - 1) & 1) * HB_SLOT;
    Pp = ws + OFF_P1 + (t & 1) * PX_SLOT;
    cp = wsw + OFF_C1; hbw = wsw + OFF_H1B + (t & 1) * HB_SLOT;
    hfw = wsw + OFF_H1F + (t & 1) * HF_SLOT;
  }

  if (t > TPREC) {
    // ================ bf16 MFMA fast path (K=512, N=64) ================
    // Wl fill: 64KB slice, swizzle byte ^= (row&7)<<4
    {
      const size_t woff = (role == 0) ? OFF_WXP : (role == 1) ? OFF_WH0
                        : (role == 2) ? OFF_WX1 : OFF_WH1;
      const char* wsrc = ws + woff + (size_t)grp * 65536;
      for (int e = tid * 8; e < 32768; e += 2048) {
        i32x4 v = *(const i32x4*)(wsrc + e * 2);
        int row = e >> 9;
        *(i32x4*)(Wl + ((e * 2) ^ ((row & 7) << 4))) = v;
      }
    }
    // A prefetch: areg[16] (chunks kc=0..3 of [64][128])
    i32x4 areg[16];
#pragma unroll
    for (int kc = 0; kc < 4; ++kc)
#pragma unroll
      for (int it = 0; it < 4; ++it) {
        const int idx = it * 2048 + tid * 8, row = idx >> 7, col = idx & 127;
        if (role == 0) {
          const float* p = xs + row * 512 + kc * 128 + col;
          const f32x4 lo = *(const f32x4*)p, hi = *(const f32x4*)(p + 4);
          i32x4 v;
          v[0] = pack2(lo[0], lo[1]); v[1] = pack2(lo[2], lo[3]);
          v[2] = pack2(hi[0], hi[1]); v[3] = pack2(hi[2], hi[3]);
          areg[kc * 4 + it] = v;
        } else {
          areg[kc * 4 + it] = ring_load16(aring + (row * 512 + kc * 128 + col) * 2);
        }
      }
    // recur roles: prefetch P (pre-activations incl bias) + c-state
    const int ucol = grp * 16 + lr;            // recur-role unit column
    float pp[4][4], cold[4];
    float kk = 0.0f;
    if (role == 1 || role == 3) {
#pragma unroll
      for (int i = 0; i < 4; ++i) {
        const int b = wv * 16 + lq * 4 + i;
#pragma unroll
        for (int gt = 0; gt < 4; ++gt)
          pp[gt][i] = ring_loadf(Pp + (b * 2048 + gt * 512 + ucol) * 4);
        cold[i] = *(const float*)(cp + (b * 512 + ucol) * 4);
      }
      kk = ktabp[(size_t)t * 1024 + (role == 3 ? 512 : 0) + ucol];
    }
    // K-loop: 4 chunks x [64][128], MFMA against Wl
    f32x4 acc[4] = {};
#pragma unroll
    for (int kc = 0; kc < 4; ++kc) {
      __syncthreads();
#pragma unroll
      for (int it = 0; it < 4; ++it) {
        const int idx = it * 2048 + tid * 8, row = idx >> 7, col = idx & 127;
        *(i32x4*)(Al + (((row * 128 + col) * 2) ^ ((row & 7) << 4))) = areg[kc * 4 + it];
      }
      __syncthreads();
#pragma unroll
      for (int ks = 0; ks < 4; ++ks) {
        const int b = wv * 16 + lr;
        const bf16x8 af = lds_frag(Al + (((b * 128 + ks * 32 + lq * 8) * 2) ^ ((b & 7) << 4)));
#pragma unroll
        for (int nt = 0; nt < 4; ++nt) {
          const int j = nt * 16 + lr;
          const bf16x8 bf = lds_frag(Wl + (((j * 512 + kc * 128 + ks * 32 + lq * 8) * 2) ^ ((j & 7) << 4)));
          acc[nt] = mfma16(af, bf, acc[nt]);
        }
      }
    }
    // C layout: col = lane&15 (within N-tile), row = wv*16 + lq*4 + i (batch)
    if (role == 0 || role == 2) {
      // project roles: store f32 pre-activations + bias
#pragma unroll
      for (int nt = 0; nt < 4; ++nt)
#pragma unroll
        for (int i = 0; i < 4; ++i) {
          const int b = wv * 16 + lq * 4 + i;
          const int n = (role == 0) ? (grp * 64 + nt * 16 + lr)
                                    : (nt * 512 + grp * 16 + lr);
          const float bv = bias[(role == 0 ? 0 : 2048) + n];
          ring_storef(dst + (b * 2048 + n) * 4, acc[nt][i] + bv);
        }
    } else {
      // recur roles: LSTM epilogue in-register (acc[gate][i])
#pragma unroll
      for (int i = 0; i < 4; ++i) {
        const int b = wv * 16 + lq * 4 + i;
        const float gi = acc[0][i] + pp[0][i];
        const float gf = acc[1][i] + pp[1][i];
        const float gz = acc[2][i] + pp[2][i];
        const float go = acc[3][i] + pp[3][i];
        const float itg = sigm(gi) * kk;
        const float ftg = sigm(gf + 1.0f - kk);
        const float gtg = tanhfast(gz) * kk;
        const float otg = sigm(go) * kk;
        const float cn = ftg * cold[i] + itg * gtg;
        const float hn = otg * tanhfast(cn);
        *(float*)(cp + (b * 512 + ucol) * 4) = cn;
        ring_store_u16(hbw + (b * 512 + ucol) * 2, (unsigned)f2bf(hn));
        if (role == 3) out[(size_t)t * 32768 + b * 512 + ucol] = hn;
        if (t == 1023) {
          const int rl = (role == 3) ? 1 : 0;
          out[33554432 + rl * 32768 + b * 512 + ucol] = hn;
          out[33554432 + 65536 + rl * 32768 + b * 512 + ucol] = cn;
        }
      }
    }
  } else {
    // ================ exact fp32 path (K=512, N=64) ================
    const int rp = tid >> 4, bq = tid & 15;
    // weight rows (original fp32 arrays)
    const float* wbase;
    if (role == 0) {
      wbase = Wxh_w + (size_t)(grp * 64 + rp * 4) * 512;
    } else {
      const int gate = rp >> 2;
      const size_t rowb = (size_t)(gate * 512 + grp * 16 + (rp & 3) * 4) * 512;
      wbase = (role == 1) ? (Whh_w + rowb)
            : (role == 2) ? (Wxh_w + 1048576 + rowb)
                          : (Whh_w + 1048576 + rowb);
    }
    // f32 A source
    const char* hsrc = nullptr;
    if (role == 1)      hsrc = ws + OFF_H0F + ((t - 1) & 1) * HF_SLOT;
    else if (role == 2) hsrc = ws + OFF_H0F + (t & 1) * HF_SLOT;
    else if (role == 3) hsrc = ws + OFF_H1F + ((t - 1) & 1) * HF_SLOT;

    f32x4 acc4[4] = {};
    for (int kc = 0; kc < 8; ++kc) {
      const int k0 = kc * 64;
      __syncthreads();
      if (role == 0) {
        // stage x chunk transposed: [b][k] -> Alf[k][b]
        for (int i = 0; i < 4; ++i) {
          int qi = tid + 256 * i, b = qi >> 4, k4 = qi & 15;
          f32x4 v = *(const f32x4*)(xs + b * 512 + k0 + k4 * 4);
#pragma unroll
          for (int j = 0; j < 4; ++j) Alf[(k4 * 4 + j) * 64 + b] = v[j];
        }
      } else {
        for (int i = 0; i < 4; ++i) {
          int qi = tid + 256 * i, k = qi >> 4, b4 = qi & 15;
          i32x4 v = ring_load16(hsrc + ((k0 + k) * 64 + b4 * 4) * 4);
          *(i32x4*)(Alf + k * 64 + b4 * 4) = v;
        }
      }
      __syncthreads();
      for (int kb = 0; kb < 16; ++kb) {
        f32x4 w4[4];
#pragma unroll
        for (int r = 0; r < 4; ++r) w4[r] = *(const f32x4*)(wbase + r * 512 + k0 + kb * 4);
#pragma unroll
        for (int ks = 0; ks < 4; ++ks) {
          f32x4 hv = *(const f32x4*)(Alf + (kb * 4 + ks) * 64 + bq * 4);
#pragma unroll
          for (int r = 0; r < 4; ++r) acc4[r] += w4[r][ks] * hv;
        }
      }
    }
    // redistribute: Alf[row j][b] ; j = rp*4+r (same ordering as fast-path N)
    __syncthreads();
#pragma unroll
    for (int r = 0; r < 4; ++r)
      *(f32x4*)(Alf + (rp * 4 + r) * 64 + bq * 4) = acc4[r];
    __syncthreads();

    if (role == 0 || role == 2) {
      for (int i = 0; i < 16; ++i) {
        int e = tid + 256 * i;
        int col = e >> 6, b = e & 63;
        const int n = (role == 0) ? (grp * 64 + col)
                                  : ((col >> 4) * 512 + grp * 16 + (col & 15));
        const float bv = bias[(role == 0 ? 0 : 2048) + n];
        ring_storef(dst + (b * 2048 + n) * 4, Alf[col * 64 + b] + bv);
      }
    } else {
      for (int i = 0; i < 4; ++i) {
        int e = tid + 256 * i;
        int u = e >> 6, b = e & 63;
        const int uc = grp * 16 + u;
        float g4[4];
#pragma unroll
        for (int gt = 0; gt < 4; ++gt)
          g4[gt] = Alf[(gt * 16 + u) * 64 + b]
                 + ring_loadf(Pp + (b * 2048 + gt * 512 + uc) * 4);
        const float kk2 = ktabp[(size_t)t * 1024 + (role == 3 ? 512 : 0) + uc];
        const float cold2 = *(const float*)(cp + (b * 512 + uc) * 4);
        const float itg = sigm(g4[0]) * kk2;
        const float ftg = sigm(g4[1] + 1.0f - kk2);
        const float gtg = tanhfast(g4[2]) * kk2;
        const float otg = sigm(g4[3]) * kk2;
        const float cn = ftg * cold2 + itg * gtg;
        const float hn = otg * tanhfast(cn);
        *(float*)(cp + (b * 512 + uc) * 4) = cn;
        ring_store_u16(hbw + (b * 512 + uc) * 2, (unsigned)f2bf(hn));
        ring_storef(hfw + (uc * 64 + b) * 4, hn);
        if (role == 3) out[(size_t)t * 32768 + b * 512 + uc] = hn;
      }
    }
  }
}

extern "C" void kernel_launch(void* const* d_in, const int* in_sizes, int n_in,
                              void* d_out, int out_size, void* d_ws, size_t ws_size,
                              hipStream_t stream) {
  (void)in_sizes; (void)n_in; (void)out_size; (void)ws_size;
  const float* inputs = (const float*)d_in[0];
  const float* times  = (const float*)d_in[1];
  const float* Wxh_w  = (const float*)d_in[2];
  const float* Wxh_b  = (const float*)d_in[3];
  const float* Whh_w  = (const float*)d_in[4];
  const float* tau    = (const float*)d_in[5];
  const float* s_p    = (const float*)d_in[6];
  unsigned char* ws = (unsigned char*)d_ws;
  float* out = (float*)d_out;

  hipMemsetAsync(ws + OFF_H0B + HB_SLOT, 0, HB_SLOT, stream);   // h0b[-1] = 0
  hipMemsetAsync(ws + OFF_H1B + HB_SLOT, 0, HB_SLOT, stream);   // h1b[-1] = 0
  hipMemsetAsync(ws + OFF_H0F + HF_SLOT, 0, HF_SLOT, stream);   // h0f[-1] = 0
  hipMemsetAsync(ws + OFF_H1F + HF_SLOT, 0, HF_SLOT, stream);   // h1f[-1] = 0
  hipMemsetAsync(ws + OFF_C0, 0, 131072, stream);               // c0 = 0
  hipMemsetAsync(ws + OFF_C1, 0, 131072, stream);               // c1 = 0

  plstm_prep<<<8192, 256, 0, stream>>>(Wxh_w, Whh_w, times, tau, s_p, ws);

  for (int q = 0; q <= 1026; ++q)
    plstm_step<<<128, 256, 0, stream>>>(inputs, Wxh_b, Wxh_w, Whh_w, out, ws, q);
}